// Round 3
// baseline (1488.554 us; speedup 1.0000x reference)
//
#include <hip/hip_runtime.h>
#include <stdint.h>

#define NN_NODE 50000
#define NN_EDGE 800000

typedef _Float16 f16;
typedef _Float16 f16x2 __attribute__((ext_vector_type(2)));
typedef _Float16 f16x8 __attribute__((ext_vector_type(8)));
typedef float f32x4 __attribute__((ext_vector_type(4)));
typedef float f32x16 __attribute__((ext_vector_type(16)));

// ---- workspace layout ----
// f16 weight area (element offsets), transposed to [N][Kpad]
#define WT_MW0   0        // [256][32]  (K=10 padded to 32)
#define WT_MW1   8192     // [256][256]
#define WT_MW2   73728    // [128][256]
#define WT_AW0   106496   // [128][128]
#define WT_AW1   122880   // [128][128]
#define WT_VW0   139264   // [256][128]
#define WT_VW1   172032   // [128][256]
#define WT_UW0   204800   // [256][128]
#define WT_UW1   237568   // [256][256]
#define WT_TOTAL 303104

// byte offsets (total = 234,606,208 B)
#define V_OFF      606208ull                  // f16 v[E][128]   (receiver-sorted)
#define WL_OFF     205406208ull               // float wlog[E]   (receiver-sorted)
#define CNT_OFF    208606208ull               // int cnt/cursor[N]
#define BASE_OFF   208806208ull               // int base[N]
#define AGGR_OFF   209006208ull               // float aggr[N][128]

// XOR-swizzled LDS addressing: rows of 256 f16 = 32 chunks of 8 f16 (16B).
// chunk' = chunk ^ (row & 7) -> per-16-lane-phase conflict-free ds_read_b128.
__device__ __forceinline__ int swz(int row, int col) {
    return row * 256 + ((((col >> 3) ^ (row & 7))) << 3) + (col & 7);
}

// ---- 32-row MLP layer using v_mfma_f32_32x32x16_f16 ----
// A-frag: m=lane&31, k=(lane>>5)*8+j. B-frag: n=lane&31, k=(lane>>5)*8+j.
// C/D:    col=lane&31, row=(reg&3)+8*(reg>>2)+4*(lane>>5).
template<int K, int N>
__device__ __forceinline__ void mfma_layer32(const f16* in, int inoff,
        const f16* __restrict__ wt, const float* __restrict__ bias,
        f16* out, int outoff, int tid)
{
    const int wave = tid >> 6;
    const int lane = tid & 63;
    const int l31  = lane & 31;
    const int kh   = lane >> 5;        // k-half select
    constexpr int NCT = N >> 5;        // 32-col tiles
    constexpr int NKS = K >> 4;        // 16-k steps
#pragma unroll 1
    for (int ct = wave; ct < NCT; ct += 4) {
        const int n = ct * 32 + l31;
        const f16* wrow = wt + (size_t)n * K + kh * 8;
        f16x8 bf[NKS];
#pragma unroll
        for (int ks = 0; ks < NKS; ++ks) bf[ks] = *(const f16x8*)(wrow + ks * 16);
        const float bv = bias[n];
        f32x16 acc = {0.f,0.f,0.f,0.f,0.f,0.f,0.f,0.f,0.f,0.f,0.f,0.f,0.f,0.f,0.f,0.f};
#pragma unroll
        for (int ks = 0; ks < NKS; ++ks) {
            const f16x8 af = *(const f16x8*)(in + swz(l31, inoff + ks * 16 + kh * 8));
            acc = __builtin_amdgcn_mfma_f32_32x32x16_f16(af, bf[ks], acc, 0, 0, 0);
        }
#pragma unroll
        for (int reg = 0; reg < 16; ++reg) {
            const int row = (reg & 3) + 8 * (reg >> 2) + 4 * kh;
            float y = acc[reg] + bv;
            y = fmaxf(y, 0.f);
            out[swz(row, outoff + n)] = (f16)y;
        }
    }
}

// ---- prep: transpose-convert weights to f16 [N][Kpad] ----
struct WSeg { const float* src; int K, N, Kpad, dstOff; };
struct WSegs { WSeg s[9]; };

__global__ void prep_kernel(WSegs segs, f16* __restrict__ wt) {
    int idx = blockIdx.x * 256 + threadIdx.x;
    if (idx >= WT_TOTAL) return;
    int off = idx;
#pragma unroll
    for (int i = 0; i < 9; ++i) {
        int sz = segs.s[i].N * segs.s[i].Kpad;
        if (off < sz) {
            int n = off / segs.s[i].Kpad;
            int k = off - n * segs.s[i].Kpad;
            f16 val = (f16)0.f;
            if (k < segs.s[i].K) val = (f16)segs.s[i].src[k * segs.s[i].N + n];
            wt[segs.s[i].dstOff + off] = val;
            return;
        }
        off -= sz;
    }
}

// ---- sort step 1: histogram of receivers ----
__global__ void hist_kernel(const int* __restrict__ receivers, int* __restrict__ cnt) {
    int e = blockIdx.x * 256 + threadIdx.x;
    atomicAdd(&cnt[receivers[e]], 1);
}

// ---- sort step 2: exclusive scan; cnt becomes cursor, base keeps copy ----
__global__ __launch_bounds__(1024) void scan_kernel(int* __restrict__ cnt, int* __restrict__ base) {
    __shared__ int psum[1024];
    const int tid = threadIdx.x;
    const int CH = (NN_NODE + 1023) / 1024;   // 49
    const int lo = tid * CH;
    const int hi = min(lo + CH, NN_NODE);
    int s = 0;
    for (int i = lo; i < hi; ++i) s += cnt[i];
    psum[tid] = s;
    __syncthreads();
    for (int d = 1; d < 1024; d <<= 1) {
        int v = (tid >= d) ? psum[tid - d] : 0;
        __syncthreads();
        psum[tid] += v;
        __syncthreads();
    }
    int run = psum[tid] - s;
    for (int i = lo; i < hi; ++i) {
        int c = cnt[i];
        base[i] = run;
        cnt[i] = run;          // cursor
        run += c;
    }
}

// ---- K1: per-edge encoder + attention logit + value; 32 edges/block ----
__global__ __launch_bounds__(256, 4) void edge_kernel(
        const float* __restrict__ nodes, const float* __restrict__ edges,
        const int* __restrict__ senders, const int* __restrict__ receivers,
        const f16* __restrict__ wt,
        const float* __restrict__ mb0, const float* __restrict__ mb1, const float* __restrict__ mb2,
        const float* __restrict__ ab0, const float* __restrict__ ab1,
        const float* __restrict__ aw2, const float* __restrict__ ab2,
        const float* __restrict__ vb0, const float* __restrict__ vb1,
        f16* __restrict__ vout, float* __restrict__ wlog, int* __restrict__ cursor)
{
    __shared__ f16 ldsbuf[2 * 32 * 256];   // 32 KB
    __shared__ int spos[32];
    f16* bufA = ldsbuf;
    f16* bufB = ldsbuf + 32 * 256;
    const int tid = threadIdx.x;
    const int e0 = blockIdx.x * 32;

    // stage z = [nodes[s], nodes[r], edge] into bufA cols 0..9, zero 10..31
    {
        int e = tid & 31, part = tid >> 5;
        if (part == 0) {
            int s = senders[e0 + e];
            for (int c = 0; c < 3; ++c) bufA[swz(e, c)] = (f16)nodes[s * 3 + c];
        } else if (part == 1) {
            int r = receivers[e0 + e];
            for (int c = 0; c < 3; ++c) bufA[swz(e, 3 + c)] = (f16)nodes[r * 3 + c];
        } else if (part == 2) {
            const float4 ev = *(const float4*)(edges + (size_t)(e0 + e) * 4);
            bufA[swz(e, 6)] = (f16)ev.x; bufA[swz(e, 7)] = (f16)ev.y;
            bufA[swz(e, 8)] = (f16)ev.z; bufA[swz(e, 9)] = (f16)ev.w;
        } else if (part == 3) {
            for (int c = 10; c < 32; ++c) bufA[swz(e, c)] = (f16)0.f;
        }
    }
    __syncthreads();

    mfma_layer32< 32, 256>(bufA, 0, wt + WT_MW0, mb0, bufB, 0, tid); __syncthreads();
    mfma_layer32<256, 256>(bufB, 0, wt + WT_MW1, mb1, bufA, 0, tid); __syncthreads();
    mfma_layer32<256, 128>(bufA, 0, wt + WT_MW2, mb2, bufB, 0, tid); __syncthreads(); // q in bufB
    mfma_layer32<128, 128>(bufB, 0, wt + WT_AW0, ab0, bufA, 0, tid); __syncthreads();
    mfma_layer32<128, 128>(bufA, 0, wt + WT_AW1, ab1, bufA, 128, tid); __syncthreads(); // cols 128..255

    // attention logit: dot(bufA[:,128:256], aw2) + ab2 ; claim sorted slot
    {
        int e = tid >> 3, part = tid & 7;
        float sum = 0.f;
        for (int c = part * 16; c < part * 16 + 16; ++c)
            sum += (float)bufA[swz(e, 128 + c)] * aw2[c];
        sum += __shfl_down(sum, 4);
        sum += __shfl_down(sum, 2);
        sum += __shfl_down(sum, 1);
        if (part == 0) {
            float wv = sum + ab2[0];
            int r = receivers[e0 + e];
            int pos = atomicAdd(&cursor[r], 1);
            spos[e] = pos;
            wlog[pos] = wv;
        }
    }
    __syncthreads();

    mfma_layer32<128, 256>(bufB, 0, wt + WT_VW0, vb0, bufA, 0, tid); __syncthreads();
    mfma_layer32<256, 128>(bufA, 0, wt + WT_VW1, vb1, bufB, 0, tid); __syncthreads(); // v in bufB

    // store v (f16, de-swizzled) to its receiver-sorted slot
    {
        int row = tid >> 3, j = tid & 7;
        uint4* dst = (uint4*)(vout + (size_t)spos[row] * 128);
#pragma unroll
        for (int i = 0; i < 2; ++i) {
            int chunk = j * 2 + i;  // 16 chunks of 8 f16 per row
            const uint4 val = *(const uint4*)(bufB + row * 256 + ((chunk ^ (row & 7)) * 8));
            dst[chunk] = val;
        }
    }
}

// ---- K2: per-node segmented softmax + weighted aggregation (1 wave / node) ----
__global__ __launch_bounds__(256) void aggregate_kernel(
        const float* __restrict__ wlog, const f16* __restrict__ v,
        const int* __restrict__ base, float* __restrict__ aggr)
{
    const int tid = threadIdx.x;
    const int n = blockIdx.x * 4 + (tid >> 6);
    const int lane = tid & 63;
    const int st = base[n];
    const int en = (n == NN_NODE - 1) ? NN_EDGE : base[n + 1];

    float mx = -1e9f;
    for (int i = st + lane; i < en; i += 64) mx = fmaxf(mx, wlog[i]);
#pragma unroll
    for (int d = 1; d < 64; d <<= 1) mx = fmaxf(mx, __shfl_xor(mx, d));

    float sm = 0.f;
    for (int i = st + lane; i < en; i += 64) sm += __expf(wlog[i] - mx);
#pragma unroll
    for (int d = 1; d < 64; d <<= 1) sm += __shfl_xor(sm, d);
    const float inv = 1.f / (sm + 1e-12f);

    float acc0 = 0.f, acc1 = 0.f;
    const f16* vp = v + (size_t)st * 128 + lane * 2;
    for (int i = st; i < en; ++i, vp += 128) {
        float attn = __expf(wlog[i] - mx) * inv;
        f16x2 vv = *(const f16x2*)vp;
        acc0 += attn * (float)vv[0];
        acc1 += attn * (float)vv[1];
    }
    float2 o; o.x = acc0; o.y = acc1;
    *(float2*)(aggr + (size_t)n * 128 + lane * 2) = o;
}

// ---- K3: node decoder (32-row tiles, tail-guarded) ----
__global__ __launch_bounds__(256, 4) void node_kernel(
        const float* __restrict__ aggr, const f16* __restrict__ wt,
        const float* __restrict__ ub0, const float* __restrict__ ub1,
        const float* __restrict__ uw2, const float* __restrict__ ub2,
        float* __restrict__ out)
{
    __shared__ f16 ldsbuf[2 * 32 * 256];
    f16* bufA = ldsbuf;
    f16* bufB = ldsbuf + 32 * 256;
    const int tid = threadIdx.x;
    const int n0 = blockIdx.x * 32;
    {
        int row = tid >> 3, j = tid & 7;   // 32 rows x 8 parts of 16 cols
        int n = n0 + row;
        if (n < NN_NODE) {
            const float4* src = (const float4*)(aggr + (size_t)n * 128 + j * 16);
#pragma unroll
            for (int i = 0; i < 4; ++i) {
                float4 t4 = src[i];
                int c = j * 16 + i * 4;
                bufA[swz(row, c + 0)] = (f16)t4.x;
                bufA[swz(row, c + 1)] = (f16)t4.y;
                bufA[swz(row, c + 2)] = (f16)t4.z;
                bufA[swz(row, c + 3)] = (f16)t4.w;
            }
        } else {
#pragma unroll
            for (int i = 0; i < 16; ++i) bufA[swz(row, j * 16 + i)] = (f16)0.f;
        }
    }
    __syncthreads();
    mfma_layer32<128, 256>(bufA, 0, wt + WT_UW0, ub0, bufB, 0, tid); __syncthreads();
    mfma_layer32<256, 256>(bufB, 0, wt + WT_UW1, ub1, bufA, 0, tid); __syncthreads();
    {
        int e = tid >> 3, part = tid & 7;
        float sum = 0.f;
        for (int c = part * 32; c < part * 32 + 32; ++c)
            sum += (float)bufA[swz(e, c)] * uw2[c];
        sum += __shfl_down(sum, 4);
        sum += __shfl_down(sum, 2);
        sum += __shfl_down(sum, 1);
        int n = n0 + e;
        if (part == 0 && n < NN_NODE) out[n] = sum + ub2[0];
    }
}

extern "C" void kernel_launch(void* const* d_in, const int* in_sizes, int n_in,
                              void* d_out, int out_size, void* d_ws, size_t ws_size,
                              hipStream_t stream)
{
    const float* nodes     = (const float*)d_in[0];
    const float* edges     = (const float*)d_in[1];
    const int*   senders   = (const int*)d_in[2];
    const int*   receivers = (const int*)d_in[3];
    const float* mw0 = (const float*)d_in[4];  const float* mb0 = (const float*)d_in[5];
    const float* mw1 = (const float*)d_in[6];  const float* mb1 = (const float*)d_in[7];
    const float* mw2 = (const float*)d_in[8];  const float* mb2 = (const float*)d_in[9];
    const float* aw0 = (const float*)d_in[10]; const float* ab0 = (const float*)d_in[11];
    const float* aw1 = (const float*)d_in[12]; const float* ab1 = (const float*)d_in[13];
    const float* aw2 = (const float*)d_in[14]; const float* ab2 = (const float*)d_in[15];
    const float* vw0 = (const float*)d_in[16]; const float* vb0 = (const float*)d_in[17];
    const float* vw1 = (const float*)d_in[18]; const float* vb1 = (const float*)d_in[19];
    const float* uw0 = (const float*)d_in[20]; const float* ub0 = (const float*)d_in[21];
    const float* uw1 = (const float*)d_in[22]; const float* ub1 = (const float*)d_in[23];
    const float* uw2 = (const float*)d_in[24]; const float* ub2 = (const float*)d_in[25];

    char* ws = (char*)d_ws;
    f16*   wt   = (f16*)ws;
    f16*   vbuf = (f16*)(ws + V_OFF);
    float* wlog = (float*)(ws + WL_OFF);
    int*   cnt  = (int*)(ws + CNT_OFF);
    int*   base = (int*)(ws + BASE_OFF);
    float* aggr = (float*)(ws + AGGR_OFF);
    float* out  = (float*)d_out;

    hipMemsetAsync(cnt, 0, NN_NODE * sizeof(int), stream);

    WSegs segs = {{
        { mw0,  10, 256,  32, WT_MW0 },
        { mw1, 256, 256, 256, WT_MW1 },
        { mw2, 256, 128, 256, WT_MW2 },
        { aw0, 128, 128, 128, WT_AW0 },
        { aw1, 128, 128, 128, WT_AW1 },
        { vw0, 128, 256, 128, WT_VW0 },
        { vw1, 256, 128, 256, WT_VW1 },
        { uw0, 128, 256, 128, WT_UW0 },
        { uw1, 256, 256, 256, WT_UW1 },
    }};
    prep_kernel<<<(WT_TOTAL + 255) / 256, 256, 0, stream>>>(segs, wt);

    hist_kernel<<<NN_EDGE / 256, 256, 0, stream>>>(receivers, cnt);
    scan_kernel<<<1, 1024, 0, stream>>>(cnt, base);

    edge_kernel<<<NN_EDGE / 32, 256, 0, stream>>>(nodes, edges, senders, receivers, wt,
        mb0, mb1, mb2, ab0, ab1, aw2, ab2, vb0, vb1, vbuf, wlog, cnt);

    aggregate_kernel<<<NN_NODE / 4, 256, 0, stream>>>(wlog, vbuf, base, aggr);

    node_kernel<<<(NN_NODE + 31) / 32, 256, 0, stream>>>(aggr, wt, ub0, ub1, uw2, ub2, out);
}

// Round 4
// 1072.571 us; speedup vs baseline: 1.3878x; 1.3878x over previous
//
#include <hip/hip_runtime.h>
#include <stdint.h>

#define NN_NODE 50000
#define NN_EDGE 800000

typedef _Float16 f16;
typedef _Float16 f16x2 __attribute__((ext_vector_type(2)));
typedef _Float16 f16x4 __attribute__((ext_vector_type(4)));
typedef _Float16 f16x8 __attribute__((ext_vector_type(8)));
typedef float f32x4 __attribute__((ext_vector_type(4)));

// ---- workspace layout ----
// f16 weight area (element offsets), transposed to [N][Kpad]
#define WT_MW0   0        // [256][32]  (K=10 padded to 32)
#define WT_MW1   8192     // [256][256]
#define WT_MW2   73728    // [128][256]
#define WT_AW0   106496   // [128][128]
#define WT_AW1   122880   // [128][128]
#define WT_VW0   139264   // [256][128]
#define WT_VW1   172032   // [128][256]
#define WT_UW0   204800   // [256][128]
#define WT_UW1   237568   // [256][256]
#define WT_TOTAL 303104

// byte offsets (total = 234,606,208 B)
#define V_OFF      606208ull                  // f16 v[E][128]   (receiver-sorted)
#define WL_OFF     205406208ull               // float wlog[E]   (receiver-sorted)
#define CNT_OFF    208606208ull               // int cnt/cursor[N]
#define BASE_OFF   208806208ull               // int base[N]
#define AGGR_OFF   209006208ull               // float aggr[N][128]

// XOR-swizzled LDS addressing: rows of 256 f16 = 32 chunks of 8 f16 (16B).
// chunk' = chunk ^ (row & 7) -> conflict-free ds_read_b128 per 16-lane phase.
__device__ __forceinline__ int swz(int row, int col) {
    return row * 256 + ((((col >> 3) ^ (row & 7))) << 3) + (col & 7);
}

// ---- MLP layer on a 64-row tile, 16x16x32 MFMA, SWAPPED operands ----
// A = weights W^T[n][k] (lane: n=lane&15 (+ct*16), k=quad*8+j)
// B = activations  (lane: edge=lane&15 (+ms*16), k=quad*8+j) -> ds_read_b128
// D: col=edge=lane&15, row=feature=quad*4+reg -> 4 contiguous features/lane
//    -> single ds_write_b64 per (ct,ms). Bias applied per-feature (float4).
// Activation fragments hoisted across ct (read once per layer): af[4][K/32].
template<int K, int N>
__device__ __forceinline__ void mfma_layer(const f16* in, int inoff,
        const f16* __restrict__ wt, const float* __restrict__ bias,
        f16* out, int outoff, int tid)
{
    const int wave = tid >> 6;
    const int lane = tid & 63;
    const int l15  = lane & 15;
    const int quad = lane >> 4;
    constexpr int NCT = N >> 4;   // 16-col tiles
    constexpr int NKS = K >> 5;   // 32-k steps

    f16x8 af[4][NKS];
#pragma unroll
    for (int ms = 0; ms < 4; ++ms)
#pragma unroll
        for (int ks = 0; ks < NKS; ++ks)
            af[ms][ks] = *(const f16x8*)(in + swz(ms * 16 + l15, inoff + ks * 32 + quad * 8));

#pragma unroll 1
    for (int ct = wave; ct < NCT; ct += 4) {
        f16x8 bf[NKS];
        const f16* wrow = wt + (size_t)(ct * 16 + l15) * K + quad * 8;
#pragma unroll
        for (int ks = 0; ks < NKS; ++ks) bf[ks] = *(const f16x8*)(wrow + ks * 32);
        const int f0 = ct * 16 + quad * 4;
        const float4 bv = *(const float4*)(bias + f0);
#pragma unroll
        for (int ms = 0; ms < 4; ++ms) {
            f32x4 acc = {0.f, 0.f, 0.f, 0.f};
#pragma unroll
            for (int ks = 0; ks < NKS; ++ks)
                acc = __builtin_amdgcn_mfma_f32_16x16x32_f16(bf[ks], af[ms][ks], acc, 0, 0, 0);
            f16x4 o;
            o[0] = (f16)fmaxf(acc[0] + bv.x, 0.f);
            o[1] = (f16)fmaxf(acc[1] + bv.y, 0.f);
            o[2] = (f16)fmaxf(acc[2] + bv.z, 0.f);
            o[3] = (f16)fmaxf(acc[3] + bv.w, 0.f);
            *(f16x4*)(out + swz(ms * 16 + l15, outoff + f0)) = o;
        }
    }
}

// ---- prep: transpose-convert weights to f16 [N][Kpad] ----
struct WSeg { const float* src; int K, N, Kpad, dstOff; };
struct WSegs { WSeg s[9]; };

__global__ void prep_kernel(WSegs segs, f16* __restrict__ wt) {
    int idx = blockIdx.x * 256 + threadIdx.x;
    if (idx >= WT_TOTAL) return;
    int off = idx;
#pragma unroll
    for (int i = 0; i < 9; ++i) {
        int sz = segs.s[i].N * segs.s[i].Kpad;
        if (off < sz) {
            int n = off / segs.s[i].Kpad;
            int k = off - n * segs.s[i].Kpad;
            f16 val = (f16)0.f;
            if (k < segs.s[i].K) val = (f16)segs.s[i].src[k * segs.s[i].N + n];
            wt[segs.s[i].dstOff + off] = val;
            return;
        }
        off -= sz;
    }
}

// ---- sort step 1: histogram of receivers ----
__global__ void hist_kernel(const int* __restrict__ receivers, int* __restrict__ cnt) {
    int e = blockIdx.x * 256 + threadIdx.x;
    atomicAdd(&cnt[receivers[e]], 1);
}

// ---- sort step 2: exclusive scan; cnt becomes cursor, base keeps copy ----
__global__ __launch_bounds__(1024) void scan_kernel(int* __restrict__ cnt, int* __restrict__ base) {
    __shared__ int psum[1024];
    const int tid = threadIdx.x;
    const int CH = (NN_NODE + 1023) / 1024;   // 49
    const int lo = tid * CH;
    const int hi = min(lo + CH, NN_NODE);
    int s = 0;
    for (int i = lo; i < hi; ++i) s += cnt[i];
    psum[tid] = s;
    __syncthreads();
    for (int d = 1; d < 1024; d <<= 1) {
        int v = (tid >= d) ? psum[tid - d] : 0;
        __syncthreads();
        psum[tid] += v;
        __syncthreads();
    }
    int run = psum[tid] - s;
    for (int i = lo; i < hi; ++i) {
        int c = cnt[i];
        base[i] = run;
        cnt[i] = run;          // cursor
        run += c;
    }
}

// ---- K1: per-edge encoder + attention logit + value; 64 edges/block ----
__global__ __launch_bounds__(256, 2) void edge_kernel(
        const float* __restrict__ nodes, const float* __restrict__ edges,
        const int* __restrict__ senders, const int* __restrict__ receivers,
        const f16* __restrict__ wt,
        const float* __restrict__ mb0, const float* __restrict__ mb1, const float* __restrict__ mb2,
        const float* __restrict__ ab0, const float* __restrict__ ab1,
        const float* __restrict__ aw2, const float* __restrict__ ab2,
        const float* __restrict__ vb0, const float* __restrict__ vb1,
        f16* __restrict__ vout, float* __restrict__ wlog, int* __restrict__ cursor)
{
    __shared__ f16 ldsbuf[2 * 64 * 256];   // 64 KB
    __shared__ int spos[64];
    f16* bufA = ldsbuf;
    f16* bufB = ldsbuf + 64 * 256;
    const int tid = threadIdx.x;
    const int e0 = blockIdx.x * 64;

    // stage z = [nodes[s], nodes[r], edge] into bufA cols 0..9, zero 10..31
    {
        int e = tid & 63, part = tid >> 6;
        if (part == 0) {
            int s = senders[e0 + e];
            for (int c = 0; c < 3; ++c) bufA[swz(e, c)] = (f16)nodes[s * 3 + c];
        } else if (part == 1) {
            int r = receivers[e0 + e];
            for (int c = 0; c < 3; ++c) bufA[swz(e, 3 + c)] = (f16)nodes[r * 3 + c];
        } else if (part == 2) {
            const float4 ev = *(const float4*)(edges + (size_t)(e0 + e) * 4);
            bufA[swz(e, 6)] = (f16)ev.x; bufA[swz(e, 7)] = (f16)ev.y;
            bufA[swz(e, 8)] = (f16)ev.z; bufA[swz(e, 9)] = (f16)ev.w;
        } else {
            for (int c = 10; c < 32; ++c) bufA[swz(e, c)] = (f16)0.f;
        }
    }
    __syncthreads();

    mfma_layer< 32, 256>(bufA, 0, wt + WT_MW0, mb0, bufB, 0, tid); __syncthreads();
    mfma_layer<256, 256>(bufB, 0, wt + WT_MW1, mb1, bufA, 0, tid); __syncthreads();
    mfma_layer<256, 128>(bufA, 0, wt + WT_MW2, mb2, bufB, 0, tid); __syncthreads(); // q in bufB
    mfma_layer<128, 128>(bufB, 0, wt + WT_AW0, ab0, bufA, 0, tid); __syncthreads();
    mfma_layer<128, 128>(bufA, 0, wt + WT_AW1, ab1, bufA, 128, tid); __syncthreads(); // cols 128..255

    // attention logit: dot(bufA[:,128:256], aw2) + ab2 ; claim sorted slot
    {
        int e = tid >> 2, part = tid & 3;
        float sum = 0.f;
        for (int c = part * 32; c < part * 32 + 32; ++c)
            sum += (float)bufA[swz(e, 128 + c)] * aw2[c];
        sum += __shfl_down(sum, 2);
        sum += __shfl_down(sum, 1);
        if (part == 0) {
            float wv = sum + ab2[0];
            int r = receivers[e0 + e];
            int pos = atomicAdd(&cursor[r], 1);
            spos[e] = pos;
            wlog[pos] = wv;
        }
    }
    __syncthreads();

    mfma_layer<128, 256>(bufB, 0, wt + WT_VW0, vb0, bufA, 0, tid); __syncthreads();
    mfma_layer<256, 128>(bufA, 0, wt + WT_VW1, vb1, bufB, 0, tid); __syncthreads(); // v in bufB

    // store v (f16, de-swizzled) to its receiver-sorted slot
    {
        int row = tid >> 2, j = tid & 3;
        uint4* dst = (uint4*)(vout + (size_t)spos[row] * 128);
#pragma unroll
        for (int i = 0; i < 4; ++i) {
            int chunk = j * 4 + i;  // 16 chunks of 8 f16 per row
            const uint4 val = *(const uint4*)(bufB + row * 256 + ((chunk ^ (row & 7)) * 8));
            dst[chunk] = val;
        }
    }
}

// ---- K2: per-node segmented softmax + weighted aggregation (1 wave / node) ----
__global__ __launch_bounds__(256) void aggregate_kernel(
        const float* __restrict__ wlog, const f16* __restrict__ v,
        const int* __restrict__ base, float* __restrict__ aggr)
{
    const int tid = threadIdx.x;
    const int n = blockIdx.x * 4 + (tid >> 6);
    const int lane = tid & 63;
    const int st = base[n];
    const int en = (n == NN_NODE - 1) ? NN_EDGE : base[n + 1];

    float mx = -1e9f;
    for (int i = st + lane; i < en; i += 64) mx = fmaxf(mx, wlog[i]);
#pragma unroll
    for (int d = 1; d < 64; d <<= 1) mx = fmaxf(mx, __shfl_xor(mx, d));

    float sm = 0.f;
    for (int i = st + lane; i < en; i += 64) sm += __expf(wlog[i] - mx);
#pragma unroll
    for (int d = 1; d < 64; d <<= 1) sm += __shfl_xor(sm, d);
    const float inv = 1.f / (sm + 1e-12f);

    float acc0 = 0.f, acc1 = 0.f;
    const f16* vp = v + (size_t)st * 128 + lane * 2;
    for (int i = st; i < en; ++i, vp += 128) {
        float attn = __expf(wlog[i] - mx) * inv;
        f16x2 vv = *(const f16x2*)vp;
        acc0 += attn * (float)vv[0];
        acc1 += attn * (float)vv[1];
    }
    float2 o; o.x = acc0; o.y = acc1;
    *(float2*)(aggr + (size_t)n * 128 + lane * 2) = o;
}

// ---- K3: node decoder (64-node tiles) ----
__global__ __launch_bounds__(256, 2) void node_kernel(
        const float* __restrict__ aggr, const f16* __restrict__ wt,
        const float* __restrict__ ub0, const float* __restrict__ ub1,
        const float* __restrict__ uw2, const float* __restrict__ ub2,
        float* __restrict__ out)
{
    __shared__ f16 ldsbuf[2 * 64 * 256];
    f16* bufA = ldsbuf;
    f16* bufB = ldsbuf + 64 * 256;
    const int tid = threadIdx.x;
    const int n0 = blockIdx.x * 64;
    {
        int row = tid >> 2, j = tid & 3;
        int n = n0 + row;
        if (n < NN_NODE) {
            const float4* src = (const float4*)(aggr + (size_t)n * 128 + j * 32);
#pragma unroll
            for (int i = 0; i < 8; ++i) {
                float4 t4 = src[i];
                int c = j * 32 + i * 4;
                bufA[swz(row, c + 0)] = (f16)t4.x;
                bufA[swz(row, c + 1)] = (f16)t4.y;
                bufA[swz(row, c + 2)] = (f16)t4.z;
                bufA[swz(row, c + 3)] = (f16)t4.w;
            }
        } else {
#pragma unroll
            for (int i = 0; i < 32; ++i) bufA[swz(row, j * 32 + i)] = (f16)0.f;
        }
    }
    __syncthreads();
    mfma_layer<128, 256>(bufA, 0, wt + WT_UW0, ub0, bufB, 0, tid); __syncthreads();
    mfma_layer<256, 256>(bufB, 0, wt + WT_UW1, ub1, bufA, 0, tid); __syncthreads();
    {
        int e = tid >> 2, part = tid & 3;
        float sum = 0.f;
        for (int c = part * 64; c < part * 64 + 64; ++c)
            sum += (float)bufA[swz(e, c)] * uw2[c];
        sum += __shfl_down(sum, 2);
        sum += __shfl_down(sum, 1);
        int n = n0 + e;
        if (part == 0 && n < NN_NODE) out[n] = sum + ub2[0];
    }
}

extern "C" void kernel_launch(void* const* d_in, const int* in_sizes, int n_in,
                              void* d_out, int out_size, void* d_ws, size_t ws_size,
                              hipStream_t stream)
{
    const float* nodes     = (const float*)d_in[0];
    const float* edges     = (const float*)d_in[1];
    const int*   senders   = (const int*)d_in[2];
    const int*   receivers = (const int*)d_in[3];
    const float* mw0 = (const float*)d_in[4];  const float* mb0 = (const float*)d_in[5];
    const float* mw1 = (const float*)d_in[6];  const float* mb1 = (const float*)d_in[7];
    const float* mw2 = (const float*)d_in[8];  const float* mb2 = (const float*)d_in[9];
    const float* aw0 = (const float*)d_in[10]; const float* ab0 = (const float*)d_in[11];
    const float* aw1 = (const float*)d_in[12]; const float* ab1 = (const float*)d_in[13];
    const float* aw2 = (const float*)d_in[14]; const float* ab2 = (const float*)d_in[15];
    const float* vw0 = (const float*)d_in[16]; const float* vb0 = (const float*)d_in[17];
    const float* vw1 = (const float*)d_in[18]; const float* vb1 = (const float*)d_in[19];
    const float* uw0 = (const float*)d_in[20]; const float* ub0 = (const float*)d_in[21];
    const float* uw1 = (const float*)d_in[22]; const float* ub1 = (const float*)d_in[23];
    const float* uw2 = (const float*)d_in[24]; const float* ub2 = (const float*)d_in[25];

    char* ws = (char*)d_ws;
    f16*   wt   = (f16*)ws;
    f16*   vbuf = (f16*)(ws + V_OFF);
    float* wlog = (float*)(ws + WL_OFF);
    int*   cnt  = (int*)(ws + CNT_OFF);
    int*   base = (int*)(ws + BASE_OFF);
    float* aggr = (float*)(ws + AGGR_OFF);
    float* out  = (float*)d_out;

    hipMemsetAsync(cnt, 0, NN_NODE * sizeof(int), stream);

    WSegs segs = {{
        { mw0,  10, 256,  32, WT_MW0 },
        { mw1, 256, 256, 256, WT_MW1 },
        { mw2, 256, 128, 256, WT_MW2 },
        { aw0, 128, 128, 128, WT_AW0 },
        { aw1, 128, 128, 128, WT_AW1 },
        { vw0, 128, 256, 128, WT_VW0 },
        { vw1, 256, 128, 256, WT_VW1 },
        { uw0, 128, 256, 128, WT_UW0 },
        { uw1, 256, 256, 256, WT_UW1 },
    }};
    prep_kernel<<<(WT_TOTAL + 255) / 256, 256, 0, stream>>>(segs, wt);

    hist_kernel<<<NN_EDGE / 256, 256, 0, stream>>>(receivers, cnt);
    scan_kernel<<<1, 1024, 0, stream>>>(cnt, base);

    edge_kernel<<<NN_EDGE / 64, 256, 0, stream>>>(nodes, edges, senders, receivers, wt,
        mb0, mb1, mb2, ab0, ab1, aw2, ab2, vb0, vb1, vbuf, wlog, cnt);

    aggregate_kernel<<<NN_NODE / 4, 256, 0, stream>>>(wlog, vbuf, base, aggr);

    node_kernel<<<(NN_NODE + 63) / 64, 256, 0, stream>>>(aggr, wt, ub0, ub1, uw2, ub2, out);
}

// Round 5
// 1029.880 us; speedup vs baseline: 1.4454x; 1.0415x over previous
//
#include <hip/hip_runtime.h>
#include <stdint.h>

#define NN_NODE 50000
#define NN_EDGE 800000

typedef _Float16 f16;
typedef _Float16 f16x2 __attribute__((ext_vector_type(2)));
typedef _Float16 f16x4 __attribute__((ext_vector_type(4)));
typedef _Float16 f16x8 __attribute__((ext_vector_type(8)));
typedef float f32x4 __attribute__((ext_vector_type(4)));

// ---- workspace layout ----
// f16 weight area (element offsets), transposed to [N][Kpad]
#define WT_MW0   0        // [256][32]  (K=10 padded to 32)
#define WT_MW1   8192     // [256][256]
#define WT_MW2   73728    // [128][256]
#define WT_AW0   106496   // [128][128]
#define WT_AW1   122880   // [128][128]
#define WT_VW0   139264   // [256][128]
#define WT_VW1   172032   // [128][256]
#define WT_UW0   204800   // [256][128]
#define WT_UW1   237568   // [256][256]
#define WT_TOTAL 303104

// byte offsets (total = 234,606,208 B)
#define V_OFF      606208ull                  // f16 v[E][128]   (receiver-sorted)
#define WL_OFF     205406208ull               // float wlog[E]   (receiver-sorted)
#define CNT_OFF    208606208ull               // int cnt/cursor[N]
#define BASE_OFF   208806208ull               // int base[N]
#define AGGR_OFF   209006208ull               // float aggr[N][128]

// XOR-swizzled LDS addressing: rows of 256 f16 = 32 chunks of 8 f16 (16B).
// chunk' = chunk ^ (row & 7) -> conflict-free ds_read_b128 per 16-lane phase.
__device__ __forceinline__ int swz(int row, int col) {
    return row * 256 + ((((col >> 3) ^ (row & 7))) << 3) + (col & 7);
}

// ---- MLP layer on a 64-row tile, 16x16x32 MFMA, swapped operands ----
// A = weights W^T[n][k] (lane: n=lane&15 (+ct*16), k=quad*8+j)
// B = activations  (lane: edge=lane&15 (+ms*16), k=quad*8+j) -> ds_read_b128
// D: col=edge=lane&15, row=feature=quad*4+reg -> 4 contiguous features/lane
//    -> single ds_write_b64 per (ct,ms).
// Weight fetches are double-buffered across ct-tiles: tile i+1's global loads
// are issued BEFORE tile i's MFMAs, so the MFMA waitcnt leaves them in flight
// (prefetch depth 1, never vmcnt(0) inside the layer).
template<int K, int N>
__device__ __forceinline__ void mfma_layer(const f16* in, int inoff,
        const f16* __restrict__ wt, const float* __restrict__ bias,
        f16* out, int outoff, int tid)
{
    const int wave = tid >> 6;
    const int lane = tid & 63;
    const int l15  = lane & 15;
    const int quad = lane >> 4;
    constexpr int NCT = N >> 4;   // 16-col tiles
    constexpr int NKS = K >> 5;   // 32-k steps
    constexpr int ITC = NCT / 4;  // ct-tiles per wave (2 or 4)

    // hoisted activation fragments (compiler may rematerialize from LDS)
    f16x8 af[4][NKS];
#pragma unroll
    for (int ms = 0; ms < 4; ++ms)
#pragma unroll
        for (int ks = 0; ks < NKS; ++ks)
            af[ms][ks] = *(const f16x8*)(in + swz(ms * 16 + l15, inoff + ks * 32 + quad * 8));

    f16x8 bf[2][NKS];
    {
        const f16* wrow = wt + (size_t)(wave * 16 + l15) * K + quad * 8;
#pragma unroll
        for (int ks = 0; ks < NKS; ++ks) bf[0][ks] = *(const f16x8*)(wrow + ks * 32);
    }
#pragma unroll
    for (int i = 0; i < ITC; ++i) {
        const int ct = wave + i * 4;
        if (i + 1 < ITC) {   // prefetch next tile's weights into alternate bank
            const f16* wrow = wt + (size_t)((ct + 4) * 16 + l15) * K + quad * 8;
#pragma unroll
            for (int ks = 0; ks < NKS; ++ks)
                bf[(i + 1) & 1][ks] = *(const f16x8*)(wrow + ks * 32);
        }
        const int f0 = ct * 16 + quad * 4;
        const float4 bv = *(const float4*)(bias + f0);
#pragma unroll
        for (int ms = 0; ms < 4; ++ms) {
            f32x4 acc = {0.f, 0.f, 0.f, 0.f};
#pragma unroll
            for (int ks = 0; ks < NKS; ++ks)
                acc = __builtin_amdgcn_mfma_f32_16x16x32_f16(bf[i & 1][ks], af[ms][ks], acc, 0, 0, 0);
            f16x4 o;
            o[0] = (f16)fmaxf(acc[0] + bv.x, 0.f);
            o[1] = (f16)fmaxf(acc[1] + bv.y, 0.f);
            o[2] = (f16)fmaxf(acc[2] + bv.z, 0.f);
            o[3] = (f16)fmaxf(acc[3] + bv.w, 0.f);
            *(f16x4*)(out + swz(ms * 16 + l15, outoff + f0)) = o;
        }
    }
}

// ---- prep: transpose-convert weights to f16 [N][Kpad] ----
struct WSeg { const float* src; int K, N, Kpad, dstOff; };
struct WSegs { WSeg s[9]; };

__global__ void prep_kernel(WSegs segs, f16* __restrict__ wt) {
    int idx = blockIdx.x * 256 + threadIdx.x;
    if (idx >= WT_TOTAL) return;
    int off = idx;
#pragma unroll
    for (int i = 0; i < 9; ++i) {
        int sz = segs.s[i].N * segs.s[i].Kpad;
        if (off < sz) {
            int n = off / segs.s[i].Kpad;
            int k = off - n * segs.s[i].Kpad;
            f16 val = (f16)0.f;
            if (k < segs.s[i].K) val = (f16)segs.s[i].src[k * segs.s[i].N + n];
            wt[segs.s[i].dstOff + off] = val;
            return;
        }
        off -= sz;
    }
}

// ---- sort step 1: histogram of receivers ----
__global__ void hist_kernel(const int* __restrict__ receivers, int* __restrict__ cnt) {
    int e = blockIdx.x * 256 + threadIdx.x;
    atomicAdd(&cnt[receivers[e]], 1);
}

// ---- sort step 2: exclusive scan; cnt becomes cursor, base keeps copy ----
__global__ __launch_bounds__(1024) void scan_kernel(int* __restrict__ cnt, int* __restrict__ base) {
    __shared__ int psum[1024];
    const int tid = threadIdx.x;
    const int CH = (NN_NODE + 1023) / 1024;   // 49
    const int lo = tid * CH;
    const int hi = min(lo + CH, NN_NODE);
    int s = 0;
    for (int i = lo; i < hi; ++i) s += cnt[i];
    psum[tid] = s;
    __syncthreads();
    for (int d = 1; d < 1024; d <<= 1) {
        int v = (tid >= d) ? psum[tid - d] : 0;
        __syncthreads();
        psum[tid] += v;
        __syncthreads();
    }
    int run = psum[tid] - s;
    for (int i = lo; i < hi; ++i) {
        int c = cnt[i];
        base[i] = run;
        cnt[i] = run;          // cursor
        run += c;
    }
}

// ---- K1: per-edge encoder + attention logit + value; 64 edges/block ----
__global__ __launch_bounds__(256, 2) void edge_kernel(
        const float* __restrict__ nodes, const float* __restrict__ edges,
        const int* __restrict__ senders, const int* __restrict__ receivers,
        const f16* __restrict__ wt,
        const float* __restrict__ mb0, const float* __restrict__ mb1, const float* __restrict__ mb2,
        const float* __restrict__ ab0, const float* __restrict__ ab1,
        const float* __restrict__ aw2, const float* __restrict__ ab2,
        const float* __restrict__ vb0, const float* __restrict__ vb1,
        f16* __restrict__ vout, float* __restrict__ wlog, int* __restrict__ cursor)
{
    __shared__ f16 ldsbuf[2 * 64 * 256];   // 64 KB
    __shared__ int spos[64];
    f16* bufA = ldsbuf;
    f16* bufB = ldsbuf + 64 * 256;
    const int tid = threadIdx.x;
    const int e0 = blockIdx.x * 64;

    // stage z = [nodes[s], nodes[r], edge] into bufA cols 0..9, zero 10..31
    {
        int e = tid & 63, part = tid >> 6;
        if (part == 0) {
            int s = senders[e0 + e];
            for (int c = 0; c < 3; ++c) bufA[swz(e, c)] = (f16)nodes[s * 3 + c];
        } else if (part == 1) {
            int r = receivers[e0 + e];
            for (int c = 0; c < 3; ++c) bufA[swz(e, 3 + c)] = (f16)nodes[r * 3 + c];
        } else if (part == 2) {
            const float4 ev = *(const float4*)(edges + (size_t)(e0 + e) * 4);
            bufA[swz(e, 6)] = (f16)ev.x; bufA[swz(e, 7)] = (f16)ev.y;
            bufA[swz(e, 8)] = (f16)ev.z; bufA[swz(e, 9)] = (f16)ev.w;
        } else {
            for (int c = 10; c < 32; ++c) bufA[swz(e, c)] = (f16)0.f;
        }
    }
    __syncthreads();

    mfma_layer< 32, 256>(bufA, 0, wt + WT_MW0, mb0, bufB, 0, tid); __syncthreads();
    mfma_layer<256, 256>(bufB, 0, wt + WT_MW1, mb1, bufA, 0, tid); __syncthreads();
    mfma_layer<256, 128>(bufA, 0, wt + WT_MW2, mb2, bufB, 0, tid); __syncthreads(); // q in bufB
    mfma_layer<128, 128>(bufB, 0, wt + WT_AW0, ab0, bufA, 0, tid); __syncthreads();
    mfma_layer<128, 128>(bufA, 0, wt + WT_AW1, ab1, bufA, 128, tid); __syncthreads(); // cols 128..255

    // attention logit: dot(bufA[:,128:256], aw2) + ab2 ; claim sorted slot
    {
        int e = tid >> 2, part = tid & 3;
        float sum = 0.f;
        for (int c = part * 32; c < part * 32 + 32; ++c)
            sum += (float)bufA[swz(e, 128 + c)] * aw2[c];
        sum += __shfl_down(sum, 2);
        sum += __shfl_down(sum, 1);
        if (part == 0) {
            float wv = sum + ab2[0];
            int r = receivers[e0 + e];
            int pos = atomicAdd(&cursor[r], 1);
            spos[e] = pos;
            wlog[pos] = wv;
        }
    }
    __syncthreads();

    mfma_layer<128, 256>(bufB, 0, wt + WT_VW0, vb0, bufA, 0, tid); __syncthreads();
    mfma_layer<256, 128>(bufA, 0, wt + WT_VW1, vb1, bufB, 0, tid); __syncthreads(); // v in bufB

    // store v (f16, de-swizzled) to its receiver-sorted slot
    {
        int row = tid >> 2, j = tid & 3;
        uint4* dst = (uint4*)(vout + (size_t)spos[row] * 128);
#pragma unroll
        for (int i = 0; i < 4; ++i) {
            int chunk = j * 4 + i;  // 16 chunks of 8 f16 per row
            const uint4 val = *(const uint4*)(bufB + row * 256 + ((chunk ^ (row & 7)) * 8));
            dst[chunk] = val;
        }
    }
}

// ---- K2: per-node segmented softmax + weighted aggregation (1 wave / node) ----
__global__ __launch_bounds__(256) void aggregate_kernel(
        const float* __restrict__ wlog, const f16* __restrict__ v,
        const int* __restrict__ base, float* __restrict__ aggr)
{
    const int tid = threadIdx.x;
    const int n = blockIdx.x * 4 + (tid >> 6);
    const int lane = tid & 63;
    const int st = base[n];
    const int en = (n == NN_NODE - 1) ? NN_EDGE : base[n + 1];

    float mx = -1e9f;
    for (int i = st + lane; i < en; i += 64) mx = fmaxf(mx, wlog[i]);
#pragma unroll
    for (int d = 1; d < 64; d <<= 1) mx = fmaxf(mx, __shfl_xor(mx, d));

    float sm = 0.f;
    for (int i = st + lane; i < en; i += 64) sm += __expf(wlog[i] - mx);
#pragma unroll
    for (int d = 1; d < 64; d <<= 1) sm += __shfl_xor(sm, d);
    const float inv = 1.f / (sm + 1e-12f);

    float acc0 = 0.f, acc1 = 0.f;
    const f16* vp = v + (size_t)st * 128 + lane * 2;
    for (int i = st; i < en; ++i, vp += 128) {
        float attn = __expf(wlog[i] - mx) * inv;
        f16x2 vv = *(const f16x2*)vp;
        acc0 += attn * (float)vv[0];
        acc1 += attn * (float)vv[1];
    }
    float2 o; o.x = acc0; o.y = acc1;
    *(float2*)(aggr + (size_t)n * 128 + lane * 2) = o;
}

// ---- K3: node decoder (64-node tiles) ----
__global__ __launch_bounds__(256, 2) void node_kernel(
        const float* __restrict__ aggr, const f16* __restrict__ wt,
        const float* __restrict__ ub0, const float* __restrict__ ub1,
        const float* __restrict__ uw2, const float* __restrict__ ub2,
        float* __restrict__ out)
{
    __shared__ f16 ldsbuf[2 * 64 * 256];
    f16* bufA = ldsbuf;
    f16* bufB = ldsbuf + 64 * 256;
    const int tid = threadIdx.x;
    const int n0 = blockIdx.x * 64;
    {
        int row = tid >> 2, j = tid & 3;
        int n = n0 + row;
        if (n < NN_NODE) {
            const float4* src = (const float4*)(aggr + (size_t)n * 128 + j * 32);
#pragma unroll
            for (int i = 0; i < 8; ++i) {
                float4 t4 = src[i];
                int c = j * 32 + i * 4;
                bufA[swz(row, c + 0)] = (f16)t4.x;
                bufA[swz(row, c + 1)] = (f16)t4.y;
                bufA[swz(row, c + 2)] = (f16)t4.z;
                bufA[swz(row, c + 3)] = (f16)t4.w;
            }
        } else {
#pragma unroll
            for (int i = 0; i < 32; ++i) bufA[swz(row, j * 32 + i)] = (f16)0.f;
        }
    }
    __syncthreads();
    mfma_layer<128, 256>(bufA, 0, wt + WT_UW0, ub0, bufB, 0, tid); __syncthreads();
    mfma_layer<256, 256>(bufB, 0, wt + WT_UW1, ub1, bufA, 0, tid); __syncthreads();
    {
        int e = tid >> 2, part = tid & 3;
        float sum = 0.f;
        for (int c = part * 64; c < part * 64 + 64; ++c)
            sum += (float)bufA[swz(e, c)] * uw2[c];
        sum += __shfl_down(sum, 2);
        sum += __shfl_down(sum, 1);
        int n = n0 + e;
        if (part == 0 && n < NN_NODE) out[n] = sum + ub2[0];
    }
}

extern "C" void kernel_launch(void* const* d_in, const int* in_sizes, int n_in,
                              void* d_out, int out_size, void* d_ws, size_t ws_size,
                              hipStream_t stream)
{
    const float* nodes     = (const float*)d_in[0];
    const float* edges     = (const float*)d_in[1];
    const int*   senders   = (const int*)d_in[2];
    const int*   receivers = (const int*)d_in[3];
    const float* mw0 = (const float*)d_in[4];  const float* mb0 = (const float*)d_in[5];
    const float* mw1 = (const float*)d_in[6];  const float* mb1 = (const float*)d_in[7];
    const float* mw2 = (const float*)d_in[8];  const float* mb2 = (const float*)d_in[9];
    const float* aw0 = (const float*)d_in[10]; const float* ab0 = (const float*)d_in[11];
    const float* aw1 = (const float*)d_in[12]; const float* ab1 = (const float*)d_in[13];
    const float* aw2 = (const float*)d_in[14]; const float* ab2 = (const float*)d_in[15];
    const float* vw0 = (const float*)d_in[16]; const float* vb0 = (const float*)d_in[17];
    const float* vw1 = (const float*)d_in[18]; const float* vb1 = (const float*)d_in[19];
    const float* uw0 = (const float*)d_in[20]; const float* ub0 = (const float*)d_in[21];
    const float* uw1 = (const float*)d_in[22]; const float* ub1 = (const float*)d_in[23];
    const float* uw2 = (const float*)d_in[24]; const float* ub2 = (const float*)d_in[25];

    char* ws = (char*)d_ws;
    f16*   wt   = (f16*)ws;
    f16*   vbuf = (f16*)(ws + V_OFF);
    float* wlog = (float*)(ws + WL_OFF);
    int*   cnt  = (int*)(ws + CNT_OFF);
    int*   base = (int*)(ws + BASE_OFF);
    float* aggr = (float*)(ws + AGGR_OFF);
    float* out  = (float*)d_out;

    hipMemsetAsync(cnt, 0, NN_NODE * sizeof(int), stream);

    WSegs segs = {{
        { mw0,  10, 256,  32, WT_MW0 },
        { mw1, 256, 256, 256, WT_MW1 },
        { mw2, 256, 128, 256, WT_MW2 },
        { aw0, 128, 128, 128, WT_AW0 },
        { aw1, 128, 128, 128, WT_AW1 },
        { vw0, 128, 256, 128, WT_VW0 },
        { vw1, 256, 128, 256, WT_VW1 },
        { uw0, 128, 256, 128, WT_UW0 },
        { uw1, 256, 256, 256, WT_UW1 },
    }};
    prep_kernel<<<(WT_TOTAL + 255) / 256, 256, 0, stream>>>(segs, wt);

    hist_kernel<<<NN_EDGE / 256, 256, 0, stream>>>(receivers, cnt);
    scan_kernel<<<1, 1024, 0, stream>>>(cnt, base);

    edge_kernel<<<NN_EDGE / 64, 256, 0, stream>>>(nodes, edges, senders, receivers, wt,
        mb0, mb1, mb2, ab0, ab1, aw2, ab2, vb0, vb1, vbuf, wlog, cnt);

    aggregate_kernel<<<NN_NODE / 4, 256, 0, stream>>>(wlog, vbuf, base, aggr);

    node_kernel<<<(NN_NODE + 63) / 64, 256, 0, stream>>>(aggr, wt, ub0, ub1, uw2, ub2, out);
}

// Round 6
// 995.712 us; speedup vs baseline: 1.4950x; 1.0343x over previous
//
#include <hip/hip_runtime.h>
#include <stdint.h>

#define NN_NODE 50000
#define NN_EDGE 800000

typedef _Float16 f16;
typedef _Float16 f16x2 __attribute__((ext_vector_type(2)));
typedef _Float16 f16x4 __attribute__((ext_vector_type(4)));
typedef _Float16 f16x8 __attribute__((ext_vector_type(8)));
typedef float f32x4 __attribute__((ext_vector_type(4)));

// ---- workspace layout ----
#define WT_MW0   0        // [256][32]  (K=10 padded to 32)
#define WT_MW1   8192     // [256][256]
#define WT_MW2   73728    // [128][256]
#define WT_AW0   106496   // [128][128]
#define WT_AW1   122880   // [128][128]
#define WT_VW0   139264   // [256][128]
#define WT_VW1   172032   // [128][256]
#define WT_UW0   204800   // [256][128]
#define WT_UW1   237568   // [256][256]
#define WT_TOTAL 303104

#define V_OFF      606208ull                  // f16 v[E][128]   (receiver-sorted)
#define WL_OFF     205406208ull               // float wlog[E]   (receiver-sorted)
#define CNT_OFF    208606208ull               // int cnt/cursor[N]
#define BASE_OFF   208806208ull               // int base[N]
#define AGGR_OFF   209006208ull               // float aggr[N][128]

// XOR-swizzled LDS addressing: rows of 256 f16 = 32 chunks of 8 f16 (16B).
__device__ __forceinline__ int swz(int row, int col) {
    return row * 256 + ((((col >> 3) ^ (row & 7))) << 3) + (col & 7);
}

// ---- fused MLP layer, 16x16x32 MFMA, swapped operands ----
// A = weights W^T[n][k], B = activations from LDS (ds_read_b128).
// D: col=edge=lane&15, row=feature=quad*4+reg.
// bf0: first ct-tile weights, preloaded by the PREVIOUS layer (cross-barrier
// prefetch). wtn/bfn: this layer prefetches the NEXT layer's first tile.
// EPI: 0 = relu -> LDS; 1 = logit partial (dot with aw2, no LDS out);
//      2 = relu -> direct global v-store at spos slot.
template<int K, int N, int NKN, int EPI>
__device__ __forceinline__ void mlayer(const f16* in, int inoff,
        const f16* __restrict__ wt, const float* __restrict__ bias,
        f16* out, int outoff,
        f16x8* bf0, const f16* __restrict__ wtn, f16x8* bfn,
        const float* __restrict__ aw2, float* lpart,
        f16* __restrict__ vout, const int* sposp, int tid)
{
    const int wave = tid >> 6;
    const int lane = tid & 63;
    const int l15  = lane & 15;
    const int quad = lane >> 4;
    constexpr int NKS = K >> 5;
    constexpr int NCT = N >> 4;
    constexpr int ITC = NCT / 4;

    // activation fragments for this layer (LDS, ~120cyc)
    f16x8 af[4][NKS];
#pragma unroll
    for (int ms = 0; ms < 4; ++ms)
#pragma unroll
        for (int ks = 0; ks < NKS; ++ks)
            af[ms][ks] = *(const f16x8*)(in + swz(ms * 16 + l15, inoff + ks * 32 + quad * 8));

    // cross-barrier prefetch: next layer's first ct-tile weights (L2, ~300-500cyc,
    // completes during this layer's compute; barrier drain finds them done)
    if constexpr (NKN > 0) {
        const f16* wrow = wtn + (size_t)(wave * 16 + l15) * (NKN * 32) + quad * 8;
#pragma unroll
        for (int ks = 0; ks < NKN; ++ks) bfn[ks] = *(const f16x8*)(wrow + ks * 32);
    }

    int   sposv[4];
    float preg[4];
    if constexpr (EPI == 2) {
#pragma unroll
        for (int ms = 0; ms < 4; ++ms) sposv[ms] = sposp[ms * 16 + l15];
    }
    if constexpr (EPI == 1) {
#pragma unroll
        for (int ms = 0; ms < 4; ++ms) preg[ms] = 0.f;
    }

    f16x8 bfl[2][NKS > 0 ? NKS : 1];
#pragma unroll
    for (int ks = 0; ks < NKS; ++ks) bfl[0][ks] = bf0[ks];

#pragma unroll
    for (int i = 0; i < ITC; ++i) {
        const int ct = wave + i * 4;
        if (i + 1 < ITC) {   // in-layer prefetch of next ct tile
            const f16* wrow = wt + (size_t)((ct + 4) * 16 + l15) * K + quad * 8;
#pragma unroll
            for (int ks = 0; ks < NKS; ++ks)
                bfl[(i + 1) & 1][ks] = *(const f16x8*)(wrow + ks * 32);
        }
        const int f0 = ct * 16 + quad * 4;
        const float4 bv = *(const float4*)(bias + f0);
        float4 awv;
        if constexpr (EPI == 1) awv = *(const float4*)(aw2 + f0);
#pragma unroll
        for (int ms = 0; ms < 4; ++ms) {
            f32x4 acc = {0.f, 0.f, 0.f, 0.f};
#pragma unroll
            for (int ks = 0; ks < NKS; ++ks)
                acc = __builtin_amdgcn_mfma_f32_16x16x32_f16(bfl[i & 1][ks], af[ms][ks], acc, 0, 0, 0);
            if constexpr (EPI == 0) {
                f16x4 o;
                o[0] = (f16)fmaxf(acc[0] + bv.x, 0.f);
                o[1] = (f16)fmaxf(acc[1] + bv.y, 0.f);
                o[2] = (f16)fmaxf(acc[2] + bv.z, 0.f);
                o[3] = (f16)fmaxf(acc[3] + bv.w, 0.f);
                *(f16x4*)(out + swz(ms * 16 + l15, outoff + f0)) = o;
            } else if constexpr (EPI == 1) {
                preg[ms] += fmaxf(acc[0] + bv.x, 0.f) * awv.x
                          + fmaxf(acc[1] + bv.y, 0.f) * awv.y
                          + fmaxf(acc[2] + bv.z, 0.f) * awv.z
                          + fmaxf(acc[3] + bv.w, 0.f) * awv.w;
            } else {
                f16x4 o;
                o[0] = (f16)fmaxf(acc[0] + bv.x, 0.f);
                o[1] = (f16)fmaxf(acc[1] + bv.y, 0.f);
                o[2] = (f16)fmaxf(acc[2] + bv.z, 0.f);
                o[3] = (f16)fmaxf(acc[3] + bv.w, 0.f);
                *(f16x4*)(vout + (size_t)sposv[ms] * 128 + f0) = o;
            }
        }
    }
    if constexpr (EPI == 1) {
#pragma unroll
        for (int ms = 0; ms < 4; ++ms) {
            float r = preg[ms];
            r += __shfl_xor(r, 16);
            r += __shfl_xor(r, 32);
            if (quad == 0) lpart[wave * 64 + ms * 16 + l15] = r;
        }
    }
}

// ---- simple layer variant (node_kernel) ----
template<int K, int N>
__device__ __forceinline__ void mfma_layer_basic(const f16* in, int inoff,
        const f16* __restrict__ wt, const float* __restrict__ bias,
        f16* out, int outoff, int tid)
{
    const int wave = tid >> 6;
    const int lane = tid & 63;
    const int l15  = lane & 15;
    const int quad = lane >> 4;
    constexpr int NCT = N >> 4;
    constexpr int NKS = K >> 5;
    f16x8 af[4][NKS];
#pragma unroll
    for (int ms = 0; ms < 4; ++ms)
#pragma unroll
        for (int ks = 0; ks < NKS; ++ks)
            af[ms][ks] = *(const f16x8*)(in + swz(ms * 16 + l15, inoff + ks * 32 + quad * 8));
#pragma unroll 1
    for (int ct = wave; ct < NCT; ct += 4) {
        f16x8 bf[NKS];
        const f16* wrow = wt + (size_t)(ct * 16 + l15) * K + quad * 8;
#pragma unroll
        for (int ks = 0; ks < NKS; ++ks) bf[ks] = *(const f16x8*)(wrow + ks * 32);
        const int f0 = ct * 16 + quad * 4;
        const float4 bv = *(const float4*)(bias + f0);
#pragma unroll
        for (int ms = 0; ms < 4; ++ms) {
            f32x4 acc = {0.f, 0.f, 0.f, 0.f};
#pragma unroll
            for (int ks = 0; ks < NKS; ++ks)
                acc = __builtin_amdgcn_mfma_f32_16x16x32_f16(bf[ks], af[ms][ks], acc, 0, 0, 0);
            f16x4 o;
            o[0] = (f16)fmaxf(acc[0] + bv.x, 0.f);
            o[1] = (f16)fmaxf(acc[1] + bv.y, 0.f);
            o[2] = (f16)fmaxf(acc[2] + bv.z, 0.f);
            o[3] = (f16)fmaxf(acc[3] + bv.w, 0.f);
            *(f16x4*)(out + swz(ms * 16 + l15, outoff + f0)) = o;
        }
    }
}

// ---- prep: transpose-convert weights to f16 [N][Kpad] ----
struct WSeg { const float* src; int K, N, Kpad, dstOff; };
struct WSegs { WSeg s[9]; };

__global__ void prep_kernel(WSegs segs, f16* __restrict__ wt) {
    int idx = blockIdx.x * 256 + threadIdx.x;
    if (idx >= WT_TOTAL) return;
    int off = idx;
#pragma unroll
    for (int i = 0; i < 9; ++i) {
        int sz = segs.s[i].N * segs.s[i].Kpad;
        if (off < sz) {
            int n = off / segs.s[i].Kpad;
            int k = off - n * segs.s[i].Kpad;
            f16 val = (f16)0.f;
            if (k < segs.s[i].K) val = (f16)segs.s[i].src[k * segs.s[i].N + n];
            wt[segs.s[i].dstOff + off] = val;
            return;
        }
        off -= sz;
    }
}

// ---- sort step 1: histogram of receivers ----
__global__ void hist_kernel(const int* __restrict__ receivers, int* __restrict__ cnt) {
    int e = blockIdx.x * 256 + threadIdx.x;
    atomicAdd(&cnt[receivers[e]], 1);
}

// ---- sort step 2: exclusive scan ----
__global__ __launch_bounds__(1024) void scan_kernel(int* __restrict__ cnt, int* __restrict__ base) {
    __shared__ int psum[1024];
    const int tid = threadIdx.x;
    const int CH = (NN_NODE + 1023) / 1024;
    const int lo = tid * CH;
    const int hi = min(lo + CH, NN_NODE);
    int s = 0;
    for (int i = lo; i < hi; ++i) s += cnt[i];
    psum[tid] = s;
    __syncthreads();
    for (int d = 1; d < 1024; d <<= 1) {
        int v = (tid >= d) ? psum[tid - d] : 0;
        __syncthreads();
        psum[tid] += v;
        __syncthreads();
    }
    int run = psum[tid] - s;
    for (int i = lo; i < hi; ++i) {
        int c = cnt[i];
        base[i] = run;
        cnt[i] = run;
        run += c;
    }
}

// ---- K1: per-edge encoder + attention logit + value; 64 edges/block ----
__global__ __launch_bounds__(256, 2) void edge_kernel(
        const float* __restrict__ nodes, const float* __restrict__ edges,
        const int* __restrict__ senders, const int* __restrict__ receivers,
        const f16* __restrict__ wt,
        const float* __restrict__ mb0, const float* __restrict__ mb1, const float* __restrict__ mb2,
        const float* __restrict__ ab0, const float* __restrict__ ab1,
        const float* __restrict__ aw2, const float* __restrict__ ab2,
        const float* __restrict__ vb0, const float* __restrict__ vb1,
        f16* __restrict__ vout, float* __restrict__ wlog, int* __restrict__ cursor)
{
    __shared__ f16 ldsbuf[2 * 64 * 256];   // 64 KB
    __shared__ int spos[64];
    __shared__ float lpart[256];
    f16* bufA = ldsbuf;
    f16* bufB = ldsbuf + 64 * 256;
    const int tid = threadIdx.x;
    const int e0 = blockIdx.x * 64;
    const int wave = tid >> 6;
    const int lane = tid & 63;
    const int l15  = lane & 15;
    const int quad = lane >> 4;

    f16x8 bfA[8], bfB[8];

    // preload L1's first weight tile (cross-barrier prefetch seed)
    {
        const f16* wrow = wt + WT_MW0 + (size_t)(wave * 16 + l15) * 32 + quad * 8;
        bfA[0] = *(const f16x8*)wrow;
    }

    // stage z: one b128 write per thread. Thread (e, c) owns chunk c of row e.
    // chunk0 = [s.xyz, r.xyz, edge01], chunk1 = [edge23, 0...], chunk2/3 = 0.
    {
        const int e = tid & 63, c = tid >> 6;
        f16x8 zv = {(f16)0.f,(f16)0.f,(f16)0.f,(f16)0.f,(f16)0.f,(f16)0.f,(f16)0.f,(f16)0.f};
        if (c == 0) {
            int s = senders[e0 + e];
            int r = receivers[e0 + e];
            const float2 ev = *(const float2*)(edges + (size_t)(e0 + e) * 4);
            zv[0] = (f16)nodes[s * 3 + 0]; zv[1] = (f16)nodes[s * 3 + 1]; zv[2] = (f16)nodes[s * 3 + 2];
            zv[3] = (f16)nodes[r * 3 + 0]; zv[4] = (f16)nodes[r * 3 + 1]; zv[5] = (f16)nodes[r * 3 + 2];
            zv[6] = (f16)ev.x; zv[7] = (f16)ev.y;
        } else if (c == 1) {
            const float2 ev = *(const float2*)(edges + (size_t)(e0 + e) * 4 + 2);
            zv[0] = (f16)ev.x; zv[1] = (f16)ev.y;
        }
        *(f16x8*)(bufA + e * 256 + ((c ^ (e & 7)) << 3)) = zv;
    }
    __syncthreads();

    mlayer< 32, 256, 8, 0>(bufA, 0, wt + WT_MW0, mb0, bufB, 0, bfA, wt + WT_MW1, bfB,
                           nullptr, nullptr, nullptr, nullptr, tid);
    __syncthreads();
    mlayer<256, 256, 8, 0>(bufB, 0, wt + WT_MW1, mb1, bufA, 0, bfB, wt + WT_MW2, bfA,
                           nullptr, nullptr, nullptr, nullptr, tid);
    __syncthreads();
    mlayer<256, 128, 4, 0>(bufA, 0, wt + WT_MW2, mb2, bufB, 0, bfA, wt + WT_AW0, bfB,
                           nullptr, nullptr, nullptr, nullptr, tid);   // q in bufB
    __syncthreads();
    mlayer<128, 128, 4, 0>(bufB, 0, wt + WT_AW0, ab0, bufA, 0, bfB, wt + WT_AW1, bfA,
                           nullptr, nullptr, nullptr, nullptr, tid);   // h0 in bufA
    __syncthreads();
    mlayer<128, 128, 4, 1>(bufA, 0, wt + WT_AW1, ab1, nullptr, 0, bfA, wt + WT_VW0, bfB,
                           aw2, lpart, nullptr, nullptr, tid);         // logit partials
    __syncthreads();

    // finalize logits (wave 0) while other waves run VW0
    if (tid < 64) {
        float wv = lpart[tid] + lpart[64 + tid] + lpart[128 + tid] + lpart[192 + tid] + ab2[0];
        int r = receivers[e0 + tid];
        int pos = atomicAdd(&cursor[r], 1);
        spos[tid] = pos;
        wlog[pos] = wv;
    }
    mlayer<128, 256, 8, 0>(bufB, 0, wt + WT_VW0, vb0, bufA, 0, bfB, wt + WT_VW1, bfA,
                           nullptr, nullptr, nullptr, nullptr, tid);
    __syncthreads();
    mlayer<256, 128, 0, 2>(bufA, 0, wt + WT_VW1, vb1, nullptr, 0, bfA, nullptr, nullptr,
                           nullptr, nullptr, vout, spos, tid);         // v direct to global
}

// ---- K2: per-node segmented softmax + weighted aggregation (1 wave / node) ----
__global__ __launch_bounds__(256) void aggregate_kernel(
        const float* __restrict__ wlog, const f16* __restrict__ v,
        const int* __restrict__ base, float* __restrict__ aggr)
{
    const int tid = threadIdx.x;
    const int n = blockIdx.x * 4 + (tid >> 6);
    const int lane = tid & 63;
    const int st = base[n];
    const int en = (n == NN_NODE - 1) ? NN_EDGE : base[n + 1];

    float mx = -1e9f;
    for (int i = st + lane; i < en; i += 64) mx = fmaxf(mx, wlog[i]);
#pragma unroll
    for (int d = 1; d < 64; d <<= 1) mx = fmaxf(mx, __shfl_xor(mx, d));

    float sm = 0.f;
    for (int i = st + lane; i < en; i += 64) sm += __expf(wlog[i] - mx);
#pragma unroll
    for (int d = 1; d < 64; d <<= 1) sm += __shfl_xor(sm, d);
    const float inv = 1.f / (sm + 1e-12f);

    float acc0 = 0.f, acc1 = 0.f;
    const f16* vp = v + (size_t)st * 128 + lane * 2;
    for (int i = st; i < en; ++i, vp += 128) {
        float attn = __expf(wlog[i] - mx) * inv;
        f16x2 vv = *(const f16x2*)vp;
        acc0 += attn * (float)vv[0];
        acc1 += attn * (float)vv[1];
    }
    float2 o; o.x = acc0; o.y = acc1;
    *(float2*)(aggr + (size_t)n * 128 + lane * 2) = o;
}

// ---- K3: node decoder (64-node tiles) ----
__global__ __launch_bounds__(256, 2) void node_kernel(
        const float* __restrict__ aggr, const f16* __restrict__ wt,
        const float* __restrict__ ub0, const float* __restrict__ ub1,
        const float* __restrict__ uw2, const float* __restrict__ ub2,
        float* __restrict__ out)
{
    __shared__ f16 ldsbuf[2 * 64 * 256];
    f16* bufA = ldsbuf;
    f16* bufB = ldsbuf + 64 * 256;
    const int tid = threadIdx.x;
    const int n0 = blockIdx.x * 64;
    {
        int row = tid >> 2, j = tid & 3;
        int n = n0 + row;
        if (n < NN_NODE) {
            const float4* src = (const float4*)(aggr + (size_t)n * 128 + j * 32);
#pragma unroll
            for (int i = 0; i < 8; ++i) {
                float4 t4 = src[i];
                int c = j * 32 + i * 4;
                bufA[swz(row, c + 0)] = (f16)t4.x;
                bufA[swz(row, c + 1)] = (f16)t4.y;
                bufA[swz(row, c + 2)] = (f16)t4.z;
                bufA[swz(row, c + 3)] = (f16)t4.w;
            }
        } else {
#pragma unroll
            for (int i = 0; i < 32; ++i) bufA[swz(row, j * 32 + i)] = (f16)0.f;
        }
    }
    __syncthreads();
    mfma_layer_basic<128, 256>(bufA, 0, wt + WT_UW0, ub0, bufB, 0, tid); __syncthreads();
    mfma_layer_basic<256, 256>(bufB, 0, wt + WT_UW1, ub1, bufA, 0, tid); __syncthreads();
    {
        int e = tid >> 2, part = tid & 3;
        float sum = 0.f;
        for (int c = part * 64; c < part * 64 + 64; ++c)
            sum += (float)bufA[swz(e, c)] * uw2[c];
        sum += __shfl_down(sum, 2);
        sum += __shfl_down(sum, 1);
        int n = n0 + e;
        if (part == 0 && n < NN_NODE) out[n] = sum + ub2[0];
    }
}

extern "C" void kernel_launch(void* const* d_in, const int* in_sizes, int n_in,
                              void* d_out, int out_size, void* d_ws, size_t ws_size,
                              hipStream_t stream)
{
    const float* nodes     = (const float*)d_in[0];
    const float* edges     = (const float*)d_in[1];
    const int*   senders   = (const int*)d_in[2];
    const int*   receivers = (const int*)d_in[3];
    const float* mw0 = (const float*)d_in[4];  const float* mb0 = (const float*)d_in[5];
    const float* mw1 = (const float*)d_in[6];  const float* mb1 = (const float*)d_in[7];
    const float* mw2 = (const float*)d_in[8];  const float* mb2 = (const float*)d_in[9];
    const float* aw0 = (const float*)d_in[10]; const float* ab0 = (const float*)d_in[11];
    const float* aw1 = (const float*)d_in[12]; const float* ab1 = (const float*)d_in[13];
    const float* aw2 = (const float*)d_in[14]; const float* ab2 = (const float*)d_in[15];
    const float* vw0 = (const float*)d_in[16]; const float* vb0 = (const float*)d_in[17];
    const float* vw1 = (const float*)d_in[18]; const float* vb1 = (const float*)d_in[19];
    const float* uw0 = (const float*)d_in[20]; const float* ub0 = (const float*)d_in[21];
    const float* uw1 = (const float*)d_in[22]; const float* ub1 = (const float*)d_in[23];
    const float* uw2 = (const float*)d_in[24]; const float* ub2 = (const float*)d_in[25];

    char* ws = (char*)d_ws;
    f16*   wt   = (f16*)ws;
    f16*   vbuf = (f16*)(ws + V_OFF);
    float* wlog = (float*)(ws + WL_OFF);
    int*   cnt  = (int*)(ws + CNT_OFF);
    int*   base = (int*)(ws + BASE_OFF);
    float* aggr = (float*)(ws + AGGR_OFF);
    float* out  = (float*)d_out;

    hipMemsetAsync(cnt, 0, NN_NODE * sizeof(int), stream);

    WSegs segs = {{
        { mw0,  10, 256,  32, WT_MW0 },
        { mw1, 256, 256, 256, WT_MW1 },
        { mw2, 256, 128, 256, WT_MW2 },
        { aw0, 128, 128, 128, WT_AW0 },
        { aw1, 128, 128, 128, WT_AW1 },
        { vw0, 128, 256, 128, WT_VW0 },
        { vw1, 256, 128, 256, WT_VW1 },
        { uw0, 128, 256, 128, WT_UW0 },
        { uw1, 256, 256, 256, WT_UW1 },
    }};
    prep_kernel<<<(WT_TOTAL + 255) / 256, 256, 0, stream>>>(segs, wt);

    hist_kernel<<<NN_EDGE / 256, 256, 0, stream>>>(receivers, cnt);
    scan_kernel<<<1, 1024, 0, stream>>>(cnt, base);

    edge_kernel<<<NN_EDGE / 64, 256, 0, stream>>>(nodes, edges, senders, receivers, wt,
        mb0, mb1, mb2, ab0, ab1, aw2, ab2, vb0, vb1, vbuf, wlog, cnt);

    aggregate_kernel<<<NN_NODE / 4, 256, 0, stream>>>(wlog, vbuf, base, aggr);

    node_kernel<<<(NN_NODE + 63) / 64, 256, 0, stream>>>(aggr, wt, ub0, ub1, uw2, ub2, out);
}